// Round 13
// baseline (562.579 us; speedup 1.0000x reference)
//
#include <hip/hip_runtime.h>
#include <stdint.h>

typedef unsigned short ushort_t;
typedef unsigned long long u64_t;
typedef __attribute__((ext_vector_type(4))) float f32x4;
typedef __attribute__((ext_vector_type(8))) short s16x8;

#define S1_ELEMS ((size_t)1568*64*512)   // 51,380,224 elements per q/k/v/x buffer

// ---------- bf16 helpers (RNE)
__device__ __forceinline__ ushort_t f2bf(float f) {
  unsigned u = __builtin_bit_cast(unsigned, f);
  u = u + 0x7fffu + ((u >> 16) & 1u);
  return (ushort_t)(u >> 16);
}

// ---------- async global->LDS, 16B per lane (dest = uniform base + lane*16)
__device__ __forceinline__ void gl_lds16(const ushort_t* g, ushort_t* l) {
  typedef __attribute__((address_space(1))) void gvoid;
  typedef __attribute__((address_space(3))) void lvoid;
  __builtin_amdgcn_global_load_lds((gvoid*)(ushort_t*)g, (lvoid*)l, 16, 0, 0);
}

// ---------- kernel 1: merged prep — x/wq/wp f32->bf16 convert + bias gather.
__global__ void k_prep(const float* __restrict__ x, ushort_t* __restrict__ xh,
                       const float* __restrict__ wq, ushort_t* __restrict__ wqh,
                       const float* __restrict__ wp, ushort_t* __restrict__ wph,
                       const float* __restrict__ table, const int* __restrict__ rel_idx,
                       float* __restrict__ bias) {
  int blk = blockIdx.x, tid = threadIdx.x;
  if (blk < 3136) {
    long i0 = (long)blk*256 + tid;
    #pragma unroll
    for (int rep = 0; rep < 8; rep++) {
      long i = i0 + (long)rep*802816;
      float4 v0 = ((const float4*)x)[2*i];
      float4 v1 = ((const float4*)x)[2*i + 1];
      s16x8 pk;
      pk[0] = (short)f2bf(v0.x); pk[1] = (short)f2bf(v0.y);
      pk[2] = (short)f2bf(v0.z); pk[3] = (short)f2bf(v0.w);
      pk[4] = (short)f2bf(v1.x); pk[5] = (short)f2bf(v1.y);
      pk[6] = (short)f2bf(v1.z); pk[7] = (short)f2bf(v1.w);
      *(s16x8*)&xh[i*8] = pk;
    }
  } else if (blk < 3648) {
    const float* src; ushort_t* dst; long i;
    if (blk < 3520) { src = wq; dst = wqh; i = (long)(blk - 3136)*256 + tid; }
    else            { src = wp; dst = wph; i = (long)(blk - 3520)*256 + tid; }
    float4 v0 = ((const float4*)src)[2*i];
    float4 v1 = ((const float4*)src)[2*i + 1];
    s16x8 pk;
    pk[0] = (short)f2bf(v0.x); pk[1] = (short)f2bf(v0.y);
    pk[2] = (short)f2bf(v0.z); pk[3] = (short)f2bf(v0.w);
    pk[4] = (short)f2bf(v1.x); pk[5] = (short)f2bf(v1.y);
    pk[6] = (short)f2bf(v1.z); pk[7] = (short)f2bf(v1.w);
    *(s16x8*)&dst[i*8] = pk;
  } else {
    int i0 = ((blk - 3648)*256 + tid)*4;     // 65536 total
    #pragma unroll
    for (int j = 0; j < 4; j++) {
      int i = i0 + j;
      int h = i >> 12, rc = i & 4095;
      bias[i] = table[rel_idx[rc] * 16 + h];
    }
  }
}

// ================= QKV GEMM (r12 config: 4-phase counted-vmcnt, 2 barriers/tile).
struct GemmCtx {
  ushort_t* lds;
  const ushort_t *pA0, *pA1, *pB0, *pB1;
  int w, lane, wm, wn;
};

template<int BUFP, int KH, int RH, int SSEL, int SBUFP, int SU, int VM, bool BAR>
__device__ __forceinline__ void phase(const GemmCtx& C, f32x4 (&acc)[8][4], s16x8 (&bf)[4], int stau) {
  s16x8 af[4];
  #pragma unroll
  for (int t = 0; t < 4; t++)
    af[t] = *(const s16x8*)&C.lds[BUFP*32768 + ((C.wm*8 + RH*4 + t)*2 + KH)*512 + C.lane*8];
  if constexpr (RH == 0) {
    #pragma unroll
    for (int t = 0; t < 4; t++)
      bf[t] = *(const s16x8*)&C.lds[BUFP*32768 + 16384 + ((C.wn*4 + t)*2 + KH)*512 + C.lane*8];
  }
  if constexpr (SSEL == 0) {
    gl_lds16(C.pA0 + stau*64 + SU*32, C.lds + SBUFP*32768 + (4*C.w + SU)*512);
    gl_lds16(C.pA1 + stau*64 + SU*32, C.lds + SBUFP*32768 + (4*C.w + 2 + SU)*512);
  } else if constexpr (SSEL == 1) {
    gl_lds16(C.pB0 + stau*64 + SU*32, C.lds + SBUFP*32768 + 16384 + (4*C.w + SU)*512);
    gl_lds16(C.pB1 + stau*64 + SU*32, C.lds + SBUFP*32768 + 16384 + (4*C.w + 2 + SU)*512);
  }
  if constexpr (VM == 8) asm volatile("s_waitcnt vmcnt(8)" ::: "memory");
  else if constexpr (VM == 4) asm volatile("s_waitcnt vmcnt(4)" ::: "memory");
  else if constexpr (VM == 0) asm volatile("s_waitcnt vmcnt(0)" ::: "memory");
  __builtin_amdgcn_s_setprio(1);
  #pragma unroll
  for (int ta = 0; ta < 4; ta++)
    #pragma unroll
    for (int tb = 0; tb < 4; tb++)
      acc[RH*4 + ta][tb] = __builtin_amdgcn_mfma_f32_16x16x32_bf16(af[ta], bf[tb], acc[RH*4 + ta][tb], 0, 0, 0);
  __builtin_amdgcn_s_setprio(0);
  if constexpr (BAR) __builtin_amdgcn_s_barrier();
}

template<int BUFP, bool S12, bool S34, int VM2, int VM4>
__device__ __forceinline__ void ktile(const GemmCtx& C, f32x4 (&acc)[8][4], int tau) {
  s16x8 bf[4];
  phase<BUFP, 0, 0, S12 ? 0 : -1, BUFP^1, 1, -1,  false>(C, acc, bf, tau + 1);
  phase<BUFP, 0, 1, S12 ? 1 : -1, BUFP^1, 1, VM2, true >(C, acc, bf, tau + 1);
  phase<BUFP, 1, 0, S34 ? 0 : -1, BUFP,   0, -1,  false>(C, acc, bf, tau + 2);
  phase<BUFP, 1, 1, S34 ? 1 : -1, BUFP,   0, VM4, true >(C, acc, bf, tau + 2);
}

__global__ __launch_bounds__(512, 2) void k_gemm_qkv(
    const ushort_t* __restrict__ xh, const ushort_t* __restrict__ wh,
    ushort_t* __restrict__ qh, ushort_t* __restrict__ kh, ushort_t* __restrict__ vt) {
  extern __shared__ __align__(16) ushort_t lds[];
  const int tid = threadIdx.x, w = tid >> 6, lane = tid & 63;
  const int g = lane >> 4, l15 = lane & 15;
  const int wm = w >> 2, wn = w & 3;
  int flat = blockIdx.x;                 // 2352 = 8*294, bijective XCD swizzle
  int swz = (flat & 7) * 294 + (flat >> 3);
  int bx = swz % 6, by = swz / 6;

  GemmCtx C;
  C.lds = lds;
  C.pA0 = xh + ((size_t)by*256 + (size_t)(2*w)*16 + l15)*512 + g*8;
  C.pA1 = C.pA0 + 16*512;
  C.pB0 = wh + ((size_t)bx*256 + (size_t)(2*w)*16 + l15)*512 + g*8;
  C.pB1 = C.pB0 + 16*512;
  C.w = w; C.lane = lane; C.wm = wm; C.wn = wn;

  f32x4 acc[8][4];
  #pragma unroll
  for (int r = 0; r < 8; r++)
    #pragma unroll
    for (int c = 0; c < 4; c++) acc[r][c] = (f32x4){0.f, 0.f, 0.f, 0.f};

  gl_lds16(C.pA0 +  0, lds + (4*w + 0)*512);
  gl_lds16(C.pA1 +  0, lds + (4*w + 2)*512);
  gl_lds16(C.pB0 +  0, lds + 16384 + (4*w + 0)*512);
  gl_lds16(C.pB1 +  0, lds + 16384 + (4*w + 2)*512);
  gl_lds16(C.pA0 + 32, lds + (4*w + 1)*512);
  gl_lds16(C.pA1 + 32, lds + (4*w + 3)*512);
  gl_lds16(C.pB0 + 32, lds + 16384 + (4*w + 1)*512);
  gl_lds16(C.pB1 + 32, lds + 16384 + (4*w + 3)*512);
  gl_lds16(C.pA0 + 64, lds + 32768 + (4*w + 0)*512);
  gl_lds16(C.pA1 + 64, lds + 32768 + (4*w + 2)*512);
  gl_lds16(C.pB0 + 64, lds + 32768 + 16384 + (4*w + 0)*512);
  gl_lds16(C.pB1 + 64, lds + 32768 + 16384 + (4*w + 2)*512);
  asm volatile("s_waitcnt vmcnt(4)" ::: "memory");
  __builtin_amdgcn_s_barrier();

  for (int kt = 0; kt < 6; kt += 2) {
    ktile<0, true, true, 8, 8>(C, acc, kt);
    ktile<1, true, true, 8, 8>(C, acc, kt + 1);
  }
  ktile<0, true,  false, 8, 4>(C, acc, 6);
  ktile<1, false, false, 0, -1>(C, acc, 7);

  // ---- epilogue: acc -> LDS (swizzled, conflict-free), coalesced stores.
  asm volatile("" ::: "memory");
  const int sel = bx >> 1;
  if (sel < 2) {
    #pragma unroll
    for (int ra = 0; ra < 8; ra++)
      #pragma unroll
      for (int tb = 0; tb < 4; tb++)
        #pragma unroll
        for (int j = 0; j < 4; j++) {
          int row = wm*128 + ra*16 + g*4 + j;
          int col = wn*64 + tb*16 + l15;
          int r = (row >> 6)*8 + (col >> 5);
          int n = row & 63, d = col & 31;
          int byte = r*4096 + ((n*64 + d*2) ^ ((n & 12) << 3));
          *(ushort_t*)((char*)lds + byte) = f2bf(acc[ra][tb][j]);
        }
  } else {
    #pragma unroll
    for (int ra = 0; ra < 8; ra++)
      #pragma unroll
      for (int tb = 0; tb < 4; tb++) {
        int row0 = wm*128 + ra*16 + g*4;
        int col = wn*64 + tb*16 + l15;
        int r = (row0 >> 6)*8 + (col >> 5);
        int n0 = row0 & 63, d = col & 31;
        u64_t pk = (u64_t)f2bf(acc[ra][tb][0])
                 | ((u64_t)f2bf(acc[ra][tb][1]) << 16)
                 | ((u64_t)f2bf(acc[ra][tb][2]) << 32)
                 | ((u64_t)f2bf(acc[ra][tb][3]) << 48);
        int byte = r*4096 + ((d*128 + n0*2) ^ ((d & 7) << 4) ^ (((((d >> 3) ^ (n0 >> 3))) & 1) << 6));
        *(u64_t*)((char*)lds + byte) = pk;
      }
  }
  asm volatile("s_waitcnt lgkmcnt(0)" ::: "memory");
  __builtin_amdgcn_s_barrier();
  ushort_t* dst = (sel == 0) ? qh : (sel == 1) ? kh : vt;
  const int hbase = (bx & 1) * 8;
  #pragma unroll
  for (int it = 0; it < 16; it++) {
    int cg = it*512 + tid;
    int r = cg >> 8, inner = cg & 255;
    int byte;
    if (sel < 2) byte = r*4096 + ((inner*16) ^ (((inner >> 2) & 12) << 3));
    else         byte = r*4096 + ((inner*16) ^ (((inner >> 3) & 7) << 4) ^ ((((inner >> 6) ^ inner) & 1) << 6));
    s16x8 v = *(const s16x8*)((const char*)lds + byte);
    int b = by*4 + (r >> 3), h = hbase + (r & 7);
    *(s16x8*)&dst[(size_t)(b*16 + h)*2048 + inner*8] = v;
  }
}

// ================= FUSED attention + proj. Block = 1 window (64 tokens) x 16 heads.
// 8 waves: each runs 2 head-windows (r12 wave code), writing bf16 attn-out
// directly into LDS in proj's fragment-linear A layout; P uses a per-wave
// fragment-linear scratch overlaid with the proj B double-buffer.
// LDS: [0,64K) aoL (64 subtiles x 1KB, sub = h*4+ta, lane-linear);
//      [64K,128K) attn: P (w*8KB) / proj: B dbuf 2x32KB.
__global__ __launch_bounds__(512) void k_attn_proj(
    const ushort_t* __restrict__ qh, const ushort_t* __restrict__ kh,
    const ushort_t* __restrict__ vt, const float* __restrict__ bias,
    const ushort_t* __restrict__ wph, const float* __restrict__ pb,
    float* __restrict__ out) {
  extern __shared__ __align__(16) ushort_t lds[];
  ushort_t* aoL = lds;
  ushort_t* pP  = lds + 32768;
  const int tid = threadIdx.x, w = tid >> 6, lane = tid & 63;
  const int g = lane >> 4, l15 = lane & 15;
  const int b = blockIdx.x;

  // ================= attn phase =================
  #pragma unroll
  for (int hw = 0; hw < 2; hw++) {
    const int h = w*2 + hw;
    const size_t base = ((size_t)b*16 + h) * 2048;

    s16x8 qf[4], kf[4];
    #pragma unroll
    for (int t = 0; t < 4; t++) {
      size_t o = base + (size_t)(t*16 + l15)*32 + g*8;
      qf[t] = *(const s16x8*)&qh[o];
      kf[t] = *(const s16x8*)&kh[o];
    }
    s16x8 vf[2][2];
    #pragma unroll
    for (int kt = 0; kt < 2; kt++)
      #pragma unroll
      for (int nt = 0; nt < 2; nt++)
        vf[kt][nt] = *(const s16x8*)&vt[base + (size_t)(nt*16 + l15)*64 + kt*32 + g*8];

    f32x4 s[4][4];
    #pragma unroll
    for (int r = 0; r < 4; r++)
      #pragma unroll
      for (int c = 0; c < 4; c++) s[r][c] = (f32x4){0.f,0.f,0.f,0.f};
    #pragma unroll
    for (int r = 0; r < 4; r++)
      #pragma unroll
      for (int c = 0; c < 4; c++)
        s[r][c] = __builtin_amdgcn_mfma_f32_16x16x32_bf16(qf[r], kf[c], s[r][c], 0, 0, 0);

    const float invs = 0.17677669529663687f;  // 1/sqrt(32)
    const float* bh_ = bias + ((size_t)h << 12);
    #pragma unroll
    for (int r = 0; r < 4; r++)
      #pragma unroll
      for (int c = 0; c < 4; c++)
        #pragma unroll
        for (int j = 0; j < 4; j++) {
          int rr = r*16 + g*4 + j, cc = c*16 + l15;
          s[r][c][j] = s[r][c][j]*invs + bh_[rr*64 + cc];
        }

    #pragma unroll
    for (int r = 0; r < 4; r++)
      #pragma unroll
      for (int j = 0; j < 4; j++) {
        float mx = fmaxf(fmaxf(s[r][0][j], s[r][1][j]), fmaxf(s[r][2][j], s[r][3][j]));
        mx = fmaxf(mx, __shfl_xor(mx, 1));
        mx = fmaxf(mx, __shfl_xor(mx, 2));
        mx = fmaxf(mx, __shfl_xor(mx, 4));
        mx = fmaxf(mx, __shfl_xor(mx, 8));
        float p0 = __expf(s[r][0][j]-mx), p1 = __expf(s[r][1][j]-mx);
        float p2 = __expf(s[r][2][j]-mx), p3 = __expf(s[r][3][j]-mx);
        float sum = p0 + p1 + p2 + p3;
        sum += __shfl_xor(sum, 1);
        sum += __shfl_xor(sum, 2);
        sum += __shfl_xor(sum, 4);
        sum += __shfl_xor(sum, 8);
        float rv = 1.0f / sum;
        s[r][0][j] = p0*rv; s[r][1][j] = p1*rv; s[r][2][j] = p2*rv; s[r][3][j] = p3*rv;
      }

    // P store: fragment-linear per-wave scratch (conflict-free; verified bijective)
    ushort_t* Pw = pP + w*4096;
    asm volatile("s_waitcnt lgkmcnt(0)" ::: "memory");
    __builtin_amdgcn_sched_barrier(0);
    #pragma unroll
    for (int r = 0; r < 4; r++)
      #pragma unroll
      for (int c = 0; c < 4; c++)
        #pragma unroll
        for (int j = 0; j < 4; j++) {
          // rr = r*16+g*4+j, cc = c*16+l15 ->
          // idx = ((cc>>5)*4 + r)*512 + (((cc>>3)&3)*16 + (rr&15))*8 + (cc&7)
          int idx = ((c >> 1)*4 + r)*512 + ((((c & 1)*2) + (l15 >> 3))*16 + g*4 + j)*8 + (l15 & 7);
          Pw[idx] = f2bf(s[r][c][j]);
        }
    asm volatile("s_waitcnt lgkmcnt(0)" ::: "memory");
    __builtin_amdgcn_sched_barrier(0);

    // P read (lane-linear) + PV
    s16x8 pf[4][2];
    #pragma unroll
    for (int ta = 0; ta < 4; ta++)
      #pragma unroll
      for (int kt = 0; kt < 2; kt++)
        pf[ta][kt] = *(const s16x8*)&Pw[(kt*4 + ta)*512 + lane*8];

    f32x4 o[4][2];
    #pragma unroll
    for (int ta = 0; ta < 4; ta++)
      #pragma unroll
      for (int nt = 0; nt < 2; nt++) o[ta][nt] = (f32x4){0.f,0.f,0.f,0.f};
    #pragma unroll
    for (int ta = 0; ta < 4; ta++)
      #pragma unroll
      for (int nt = 0; nt < 2; nt++)
        #pragma unroll
        for (int kt = 0; kt < 2; kt++)
          o[ta][nt] = __builtin_amdgcn_mfma_f32_16x16x32_bf16(pf[ta][kt], vf[kt][nt], o[ta][nt], 0, 0, 0);

    // attn-out -> aoL in proj A fragment-linear layout (conflict-free writes)
    #pragma unroll
    for (int ta = 0; ta < 4; ta++)
      #pragma unroll
      for (int nt = 0; nt < 2; nt++)
        #pragma unroll
        for (int j = 0; j < 4; j++) {
          int idx = (h*4 + ta)*512 + ((nt*2 + (l15 >> 3))*16 + g*4 + j)*8 + (l15 & 7);
          aoL[idx] = f2bf(o[ta][nt][j]);
        }
  }

  __syncthreads();   // aoL complete across waves; P region freed for B dbuf

  // ================= proj phase (barrier-free: each wave stages+reads its own B cols)
  f32x4 acc[4][4];
  #pragma unroll
  for (int r = 0; r < 4; r++)
    #pragma unroll
    for (int c = 0; c < 4; c++) acc[r][c] = (f32x4){0.f, 0.f, 0.f, 0.f};

  ushort_t* buf0 = pP;
  ushort_t* buf1 = pP + 16384;
  const ushort_t* bsrc[4];
  #pragma unroll
  for (int q = 0; q < 4; q++)
    bsrc[q] = wph + (size_t)((4*w + q)*16 + l15)*512 + g*8;

  #pragma unroll
  for (int q = 0; q < 4; q++)
    gl_lds16(bsrc[q], buf0 + (4*w + q)*512);

  for (int t = 0; t < 16; ++t) {
    ushort_t* bufR = (t & 1) ? buf1 : buf0;
    ushort_t* bufW = (t & 1) ? buf0 : buf1;
    if (t < 15) {
      #pragma unroll
      for (int q = 0; q < 4; q++)
        gl_lds16(bsrc[q] + (t + 1)*32, bufW + (4*w + q)*512);
      asm volatile("s_waitcnt vmcnt(4)" ::: "memory");
    } else {
      asm volatile("s_waitcnt vmcnt(0)" ::: "memory");
    }
    __builtin_amdgcn_sched_barrier(0);
    s16x8 af[4], bf[4];
    #pragma unroll
    for (int ta = 0; ta < 4; ta++)
      af[ta] = *(const s16x8*)&aoL[(t*4 + ta)*512 + lane*8];
    #pragma unroll
    for (int tb = 0; tb < 4; tb++)
      bf[tb] = *(const s16x8*)&bufR[(w*4 + tb)*512 + lane*8];
    __builtin_amdgcn_s_setprio(1);
    #pragma unroll
    for (int ta = 0; ta < 4; ta++)
      #pragma unroll
      for (int tb = 0; tb < 4; tb++)
        acc[ta][tb] = __builtin_amdgcn_mfma_f32_16x16x32_bf16(af[ta], bf[tb], acc[ta][tb], 0, 0, 0);
    __builtin_amdgcn_s_setprio(0);
  }

  // epilogue: f32 stores (4 rows x 64B segments per instr) + bias
  float pbv[4];
  #pragma unroll
  for (int tb = 0; tb < 4; tb++) pbv[tb] = pb[w*64 + tb*16 + l15];
  #pragma unroll
  for (int ta = 0; ta < 4; ta++)
    #pragma unroll
    for (int tb = 0; tb < 4; tb++)
      #pragma unroll
      for (int j = 0; j < 4; j++) {
        int row = ta*16 + g*4 + j;
        int col = w*64 + tb*16 + l15;
        out[((size_t)b*64 + row)*512 + col] = acc[ta][tb][j] + pbv[tb];
      }
}

extern "C" void kernel_launch(void* const* d_in, const int* in_sizes, int n_in,
                              void* d_out, int out_size, void* d_ws, size_t ws_size,
                              hipStream_t stream) {
  const float* x      = (const float*)d_in[0];
  const float* qkv_w  = (const float*)d_in[1];
  const float* table  = (const float*)d_in[2];
  const float* proj_w = (const float*)d_in[3];
  const float* proj_b = (const float*)d_in[4];
  const int*   rel_idx = (const int*)d_in[5];

  const size_t S1 = S1_ELEMS;
  const size_t need = (4*S1 + 786432 + 262144)*sizeof(ushort_t) + 65536*sizeof(float);
  if (ws_size < need) return;

  ushort_t* qh  = (ushort_t*)d_ws;
  ushort_t* kh  = qh + S1;
  ushort_t* vt  = kh + S1;
  ushort_t* xh  = vt + S1;
  ushort_t* wqh = xh + S1;
  ushort_t* wph = wqh + 786432;
  float*    bias = (float*)(wph + 262144);

  hipFuncSetAttribute((const void*)k_gemm_qkv,
                      hipFuncAttributeMaxDynamicSharedMemorySize, 131072);
  hipFuncSetAttribute((const void*)k_attn_proj,
                      hipFuncAttributeMaxDynamicSharedMemorySize, 131072);

  k_prep<<<3712, 256, 0, stream>>>(x, xh, qkv_w, wqh, proj_w, wph, table, rel_idx, bias);
  k_gemm_qkv<<<2352, 512, 131072, stream>>>(xh, wqh, qh, kh, vt);
  k_attn_proj<<<1568, 512, 131072, stream>>>(qh, kh, vt, bias, wph, proj_b, (float*)d_out);
}

// Round 14
// 561.336 us; speedup vs baseline: 1.0022x; 1.0022x over previous
//
#include <hip/hip_runtime.h>
#include <stdint.h>

typedef unsigned short ushort_t;
typedef unsigned long long u64_t;
typedef __attribute__((ext_vector_type(4))) float f32x4;
typedef __attribute__((ext_vector_type(8))) short s16x8;

#define S1_ELEMS ((size_t)1568*64*512)   // 51,380,224 elements per q/k/v/x buffer

// ---------- bf16 helpers (RNE)
__device__ __forceinline__ ushort_t f2bf(float f) {
  unsigned u = __builtin_bit_cast(unsigned, f);
  u = u + 0x7fffu + ((u >> 16) & 1u);
  return (ushort_t)(u >> 16);
}

// ---------- async global->LDS, 16B per lane (dest = uniform base + lane*16)
__device__ __forceinline__ void gl_lds16(const ushort_t* g, ushort_t* l) {
  typedef __attribute__((address_space(1))) void gvoid;
  typedef __attribute__((address_space(3))) void lvoid;
  __builtin_amdgcn_global_load_lds((gvoid*)(ushort_t*)g, (lvoid*)l, 16, 0, 0);
}

// ---------- kernel 1: merged prep — x/wq/wp f32->bf16 convert + bias gather.
__global__ void k_prep(const float* __restrict__ x, ushort_t* __restrict__ xh,
                       const float* __restrict__ wq, ushort_t* __restrict__ wqh,
                       const float* __restrict__ wp, ushort_t* __restrict__ wph,
                       const float* __restrict__ table, const int* __restrict__ rel_idx,
                       float* __restrict__ bias) {
  int blk = blockIdx.x, tid = threadIdx.x;
  if (blk < 3136) {
    long i0 = (long)blk*256 + tid;
    #pragma unroll
    for (int rep = 0; rep < 8; rep++) {
      long i = i0 + (long)rep*802816;
      float4 v0 = ((const float4*)x)[2*i];
      float4 v1 = ((const float4*)x)[2*i + 1];
      s16x8 pk;
      pk[0] = (short)f2bf(v0.x); pk[1] = (short)f2bf(v0.y);
      pk[2] = (short)f2bf(v0.z); pk[3] = (short)f2bf(v0.w);
      pk[4] = (short)f2bf(v1.x); pk[5] = (short)f2bf(v1.y);
      pk[6] = (short)f2bf(v1.z); pk[7] = (short)f2bf(v1.w);
      *(s16x8*)&xh[i*8] = pk;
    }
  } else if (blk < 3648) {
    const float* src; ushort_t* dst; long i;
    if (blk < 3520) { src = wq; dst = wqh; i = (long)(blk - 3136)*256 + tid; }
    else            { src = wp; dst = wph; i = (long)(blk - 3520)*256 + tid; }
    float4 v0 = ((const float4*)src)[2*i];
    float4 v1 = ((const float4*)src)[2*i + 1];
    s16x8 pk;
    pk[0] = (short)f2bf(v0.x); pk[1] = (short)f2bf(v0.y);
    pk[2] = (short)f2bf(v0.z); pk[3] = (short)f2bf(v0.w);
    pk[4] = (short)f2bf(v1.x); pk[5] = (short)f2bf(v1.y);
    pk[6] = (short)f2bf(v1.z); pk[7] = (short)f2bf(v1.w);
    *(s16x8*)&dst[i*8] = pk;
  } else {
    int i0 = ((blk - 3648)*256 + tid)*4;     // 65536 total
    #pragma unroll
    for (int j = 0; j < 4; j++) {
      int i = i0 + j;
      int h = i >> 12, rc = i & 4095;
      bias[i] = table[rel_idx[rc] * 16 + h];
    }
  }
}

// ================= QKV GEMM (r12 config: 4-phase counted-vmcnt, 2 barriers/tile).
struct GemmCtx {
  ushort_t* lds;
  const ushort_t *pA0, *pA1, *pB0, *pB1;
  int w, lane, wm, wn;
};

template<int BUFP, int KH, int RH, int SSEL, int SBUFP, int SU, int VM, bool BAR>
__device__ __forceinline__ void phase(const GemmCtx& C, f32x4 (&acc)[8][4], s16x8 (&bf)[4], int stau) {
  s16x8 af[4];
  #pragma unroll
  for (int t = 0; t < 4; t++)
    af[t] = *(const s16x8*)&C.lds[BUFP*32768 + ((C.wm*8 + RH*4 + t)*2 + KH)*512 + C.lane*8];
  if constexpr (RH == 0) {
    #pragma unroll
    for (int t = 0; t < 4; t++)
      bf[t] = *(const s16x8*)&C.lds[BUFP*32768 + 16384 + ((C.wn*4 + t)*2 + KH)*512 + C.lane*8];
  }
  if constexpr (SSEL == 0) {
    gl_lds16(C.pA0 + stau*64 + SU*32, C.lds + SBUFP*32768 + (4*C.w + SU)*512);
    gl_lds16(C.pA1 + stau*64 + SU*32, C.lds + SBUFP*32768 + (4*C.w + 2 + SU)*512);
  } else if constexpr (SSEL == 1) {
    gl_lds16(C.pB0 + stau*64 + SU*32, C.lds + SBUFP*32768 + 16384 + (4*C.w + SU)*512);
    gl_lds16(C.pB1 + stau*64 + SU*32, C.lds + SBUFP*32768 + 16384 + (4*C.w + 2 + SU)*512);
  }
  if constexpr (VM == 8) asm volatile("s_waitcnt vmcnt(8)" ::: "memory");
  else if constexpr (VM == 4) asm volatile("s_waitcnt vmcnt(4)" ::: "memory");
  else if constexpr (VM == 0) asm volatile("s_waitcnt vmcnt(0)" ::: "memory");
  __builtin_amdgcn_s_setprio(1);
  #pragma unroll
  for (int ta = 0; ta < 4; ta++)
    #pragma unroll
    for (int tb = 0; tb < 4; tb++)
      acc[RH*4 + ta][tb] = __builtin_amdgcn_mfma_f32_16x16x32_bf16(af[ta], bf[tb], acc[RH*4 + ta][tb], 0, 0, 0);
  __builtin_amdgcn_s_setprio(0);
  if constexpr (BAR) __builtin_amdgcn_s_barrier();
}

template<int BUFP, bool S12, bool S34, int VM2, int VM4>
__device__ __forceinline__ void ktile(const GemmCtx& C, f32x4 (&acc)[8][4], int tau) {
  s16x8 bf[4];
  phase<BUFP, 0, 0, S12 ? 0 : -1, BUFP^1, 1, -1,  false>(C, acc, bf, tau + 1);
  phase<BUFP, 0, 1, S12 ? 1 : -1, BUFP^1, 1, VM2, true >(C, acc, bf, tau + 1);
  phase<BUFP, 1, 0, S34 ? 0 : -1, BUFP,   0, -1,  false>(C, acc, bf, tau + 2);
  phase<BUFP, 1, 1, S34 ? 1 : -1, BUFP,   0, VM4, true >(C, acc, bf, tau + 2);
}

__global__ __launch_bounds__(512, 2) void k_gemm_qkv(
    const ushort_t* __restrict__ xh, const ushort_t* __restrict__ wh,
    ushort_t* __restrict__ qh, ushort_t* __restrict__ kh, ushort_t* __restrict__ vt) {
  extern __shared__ __align__(16) ushort_t lds[];
  const int tid = threadIdx.x, w = tid >> 6, lane = tid & 63;
  const int g = lane >> 4, l15 = lane & 15;
  const int wm = w >> 2, wn = w & 3;
  int flat = blockIdx.x;                 // 2352 = 8*294, bijective XCD swizzle
  int swz = (flat & 7) * 294 + (flat >> 3);
  int bx = swz % 6, by = swz / 6;

  GemmCtx C;
  C.lds = lds;
  C.pA0 = xh + ((size_t)by*256 + (size_t)(2*w)*16 + l15)*512 + g*8;
  C.pA1 = C.pA0 + 16*512;
  C.pB0 = wh + ((size_t)bx*256 + (size_t)(2*w)*16 + l15)*512 + g*8;
  C.pB1 = C.pB0 + 16*512;
  C.w = w; C.lane = lane; C.wm = wm; C.wn = wn;

  f32x4 acc[8][4];
  #pragma unroll
  for (int r = 0; r < 8; r++)
    #pragma unroll
    for (int c = 0; c < 4; c++) acc[r][c] = (f32x4){0.f, 0.f, 0.f, 0.f};

  gl_lds16(C.pA0 +  0, lds + (4*w + 0)*512);
  gl_lds16(C.pA1 +  0, lds + (4*w + 2)*512);
  gl_lds16(C.pB0 +  0, lds + 16384 + (4*w + 0)*512);
  gl_lds16(C.pB1 +  0, lds + 16384 + (4*w + 2)*512);
  gl_lds16(C.pA0 + 32, lds + (4*w + 1)*512);
  gl_lds16(C.pA1 + 32, lds + (4*w + 3)*512);
  gl_lds16(C.pB0 + 32, lds + 16384 + (4*w + 1)*512);
  gl_lds16(C.pB1 + 32, lds + 16384 + (4*w + 3)*512);
  gl_lds16(C.pA0 + 64, lds + 32768 + (4*w + 0)*512);
  gl_lds16(C.pA1 + 64, lds + 32768 + (4*w + 2)*512);
  gl_lds16(C.pB0 + 64, lds + 32768 + 16384 + (4*w + 0)*512);
  gl_lds16(C.pB1 + 64, lds + 32768 + 16384 + (4*w + 2)*512);
  asm volatile("s_waitcnt vmcnt(4)" ::: "memory");
  __builtin_amdgcn_s_barrier();

  for (int kt = 0; kt < 6; kt += 2) {
    ktile<0, true, true, 8, 8>(C, acc, kt);
    ktile<1, true, true, 8, 8>(C, acc, kt + 1);
  }
  ktile<0, true,  false, 8, 4>(C, acc, 6);
  ktile<1, false, false, 0, -1>(C, acc, 7);

  // ---- epilogue: acc -> LDS (swizzled, conflict-free), coalesced stores.
  asm volatile("" ::: "memory");
  const int sel = bx >> 1;
  if (sel < 2) {
    #pragma unroll
    for (int ra = 0; ra < 8; ra++)
      #pragma unroll
      for (int tb = 0; tb < 4; tb++)
        #pragma unroll
        for (int j = 0; j < 4; j++) {
          int row = wm*128 + ra*16 + g*4 + j;
          int col = wn*64 + tb*16 + l15;
          int r = (row >> 6)*8 + (col >> 5);
          int n = row & 63, d = col & 31;
          int byte = r*4096 + ((n*64 + d*2) ^ ((n & 12) << 3));
          *(ushort_t*)((char*)lds + byte) = f2bf(acc[ra][tb][j]);
        }
  } else {
    #pragma unroll
    for (int ra = 0; ra < 8; ra++)
      #pragma unroll
      for (int tb = 0; tb < 4; tb++) {
        int row0 = wm*128 + ra*16 + g*4;
        int col = wn*64 + tb*16 + l15;
        int r = (row0 >> 6)*8 + (col >> 5);
        int n0 = row0 & 63, d = col & 31;
        u64_t pk = (u64_t)f2bf(acc[ra][tb][0])
                 | ((u64_t)f2bf(acc[ra][tb][1]) << 16)
                 | ((u64_t)f2bf(acc[ra][tb][2]) << 32)
                 | ((u64_t)f2bf(acc[ra][tb][3]) << 48);
        int byte = r*4096 + ((d*128 + n0*2) ^ ((d & 7) << 4) ^ (((((d >> 3) ^ (n0 >> 3))) & 1) << 6));
        *(u64_t*)((char*)lds + byte) = pk;
      }
  }
  asm volatile("s_waitcnt lgkmcnt(0)" ::: "memory");
  __builtin_amdgcn_s_barrier();
  ushort_t* dst = (sel == 0) ? qh : (sel == 1) ? kh : vt;
  const int hbase = (bx & 1) * 8;
  #pragma unroll
  for (int it = 0; it < 16; it++) {
    int cg = it*512 + tid;
    int r = cg >> 8, inner = cg & 255;
    int byte;
    if (sel < 2) byte = r*4096 + ((inner*16) ^ (((inner >> 2) & 12) << 3));
    else         byte = r*4096 + ((inner*16) ^ (((inner >> 3) & 7) << 4) ^ ((((inner >> 6) ^ inner) & 1) << 6));
    s16x8 v = *(const s16x8*)((const char*)lds + byte);
    int b = by*4 + (r >> 3), h = hbase + (r & 7);
    *(s16x8*)&dst[(size_t)(b*16 + h)*2048 + inner*8] = v;
  }
}

// ================= FUSED attention + proj. Block = 1 window (64 tokens) x 16 heads.
// 8 waves: each runs 2 head-windows (r12 wave code), writing bf16 attn-out
// directly into LDS in proj's fragment-linear A layout; P uses a per-wave
// fragment-linear scratch overlaid with the proj B double-buffer.
// LDS: [0,64K) aoL (64 subtiles x 1KB, sub = h*4+ta, lane-linear);
//      [64K,128K) attn: P (w*8KB) / proj: B dbuf 2x32KB.
__global__ __launch_bounds__(512) void k_attn_proj(
    const ushort_t* __restrict__ qh, const ushort_t* __restrict__ kh,
    const ushort_t* __restrict__ vt, const float* __restrict__ bias,
    const ushort_t* __restrict__ wph, const float* __restrict__ pb,
    float* __restrict__ out) {
  extern __shared__ __align__(16) ushort_t lds[];
  ushort_t* aoL = lds;
  ushort_t* pP  = lds + 32768;
  const int tid = threadIdx.x, w = tid >> 6, lane = tid & 63;
  const int g = lane >> 4, l15 = lane & 15;
  const int b = blockIdx.x;

  // ================= attn phase =================
  #pragma unroll
  for (int hw = 0; hw < 2; hw++) {
    const int h = w*2 + hw;
    const size_t base = ((size_t)b*16 + h) * 2048;

    s16x8 qf[4], kf[4];
    #pragma unroll
    for (int t = 0; t < 4; t++) {
      size_t o = base + (size_t)(t*16 + l15)*32 + g*8;
      qf[t] = *(const s16x8*)&qh[o];
      kf[t] = *(const s16x8*)&kh[o];
    }
    s16x8 vf[2][2];
    #pragma unroll
    for (int kt = 0; kt < 2; kt++)
      #pragma unroll
      for (int nt = 0; nt < 2; nt++)
        vf[kt][nt] = *(const s16x8*)&vt[base + (size_t)(nt*16 + l15)*64 + kt*32 + g*8];

    f32x4 s[4][4];
    #pragma unroll
    for (int r = 0; r < 4; r++)
      #pragma unroll
      for (int c = 0; c < 4; c++) s[r][c] = (f32x4){0.f,0.f,0.f,0.f};
    #pragma unroll
    for (int r = 0; r < 4; r++)
      #pragma unroll
      for (int c = 0; c < 4; c++)
        s[r][c] = __builtin_amdgcn_mfma_f32_16x16x32_bf16(qf[r], kf[c], s[r][c], 0, 0, 0);

    const float invs = 0.17677669529663687f;  // 1/sqrt(32)
    const float* bh_ = bias + ((size_t)h << 12);
    #pragma unroll
    for (int r = 0; r < 4; r++)
      #pragma unroll
      for (int c = 0; c < 4; c++)
        #pragma unroll
        for (int j = 0; j < 4; j++) {
          int rr = r*16 + g*4 + j, cc = c*16 + l15;
          s[r][c][j] = s[r][c][j]*invs + bh_[rr*64 + cc];
        }

    #pragma unroll
    for (int r = 0; r < 4; r++)
      #pragma unroll
      for (int j = 0; j < 4; j++) {
        float mx = fmaxf(fmaxf(s[r][0][j], s[r][1][j]), fmaxf(s[r][2][j], s[r][3][j]));
        mx = fmaxf(mx, __shfl_xor(mx, 1));
        mx = fmaxf(mx, __shfl_xor(mx, 2));
        mx = fmaxf(mx, __shfl_xor(mx, 4));
        mx = fmaxf(mx, __shfl_xor(mx, 8));
        float p0 = __expf(s[r][0][j]-mx), p1 = __expf(s[r][1][j]-mx);
        float p2 = __expf(s[r][2][j]-mx), p3 = __expf(s[r][3][j]-mx);
        float sum = p0 + p1 + p2 + p3;
        sum += __shfl_xor(sum, 1);
        sum += __shfl_xor(sum, 2);
        sum += __shfl_xor(sum, 4);
        sum += __shfl_xor(sum, 8);
        float rv = 1.0f / sum;
        s[r][0][j] = p0*rv; s[r][1][j] = p1*rv; s[r][2][j] = p2*rv; s[r][3][j] = p3*rv;
      }

    // P store: fragment-linear per-wave scratch (conflict-free; verified bijective)
    ushort_t* Pw = pP + w*4096;
    asm volatile("s_waitcnt lgkmcnt(0)" ::: "memory");
    __builtin_amdgcn_sched_barrier(0);
    #pragma unroll
    for (int r = 0; r < 4; r++)
      #pragma unroll
      for (int c = 0; c < 4; c++)
        #pragma unroll
        for (int j = 0; j < 4; j++) {
          // rr = r*16+g*4+j, cc = c*16+l15 ->
          // idx = ((cc>>5)*4 + r)*512 + (((cc>>3)&3)*16 + (rr&15))*8 + (cc&7)
          int idx = ((c >> 1)*4 + r)*512 + ((((c & 1)*2) + (l15 >> 3))*16 + g*4 + j)*8 + (l15 & 7);
          Pw[idx] = f2bf(s[r][c][j]);
        }
    asm volatile("s_waitcnt lgkmcnt(0)" ::: "memory");
    __builtin_amdgcn_sched_barrier(0);

    // P read (lane-linear) + PV
    s16x8 pf[4][2];
    #pragma unroll
    for (int ta = 0; ta < 4; ta++)
      #pragma unroll
      for (int kt = 0; kt < 2; kt++)
        pf[ta][kt] = *(const s16x8*)&Pw[(kt*4 + ta)*512 + lane*8];

    f32x4 o[4][2];
    #pragma unroll
    for (int ta = 0; ta < 4; ta++)
      #pragma unroll
      for (int nt = 0; nt < 2; nt++) o[ta][nt] = (f32x4){0.f,0.f,0.f,0.f};
    #pragma unroll
    for (int ta = 0; ta < 4; ta++)
      #pragma unroll
      for (int nt = 0; nt < 2; nt++)
        #pragma unroll
        for (int kt = 0; kt < 2; kt++)
          o[ta][nt] = __builtin_amdgcn_mfma_f32_16x16x32_bf16(pf[ta][kt], vf[kt][nt], o[ta][nt], 0, 0, 0);

    // attn-out -> aoL in proj A fragment-linear layout (conflict-free writes)
    #pragma unroll
    for (int ta = 0; ta < 4; ta++)
      #pragma unroll
      for (int nt = 0; nt < 2; nt++)
        #pragma unroll
        for (int j = 0; j < 4; j++) {
          int idx = (h*4 + ta)*512 + ((nt*2 + (l15 >> 3))*16 + g*4 + j)*8 + (l15 & 7);
          aoL[idx] = f2bf(o[ta][nt][j]);
        }
  }

  __syncthreads();   // aoL complete across waves; P region freed for B dbuf

  // ================= proj phase (barrier-free: each wave stages+reads its own B cols)
  f32x4 acc[4][4];
  #pragma unroll
  for (int r = 0; r < 4; r++)
    #pragma unroll
    for (int c = 0; c < 4; c++) acc[r][c] = (f32x4){0.f, 0.f, 0.f, 0.f};

  ushort_t* buf0 = pP;
  ushort_t* buf1 = pP + 16384;
  const ushort_t* bsrc[4];
  #pragma unroll
  for (int q = 0; q < 4; q++)
    bsrc[q] = wph + (size_t)((4*w + q)*16 + l15)*512 + g*8;

  #pragma unroll
  for (int q = 0; q < 4; q++)
    gl_lds16(bsrc[q], buf0 + (4*w + q)*512);

  for (int t = 0; t < 16; ++t) {
    ushort_t* bufR = (t & 1) ? buf1 : buf0;
    ushort_t* bufW = (t & 1) ? buf0 : buf1;
    if (t < 15) {
      #pragma unroll
      for (int q = 0; q < 4; q++)
        gl_lds16(bsrc[q] + (t + 1)*32, bufW + (4*w + q)*512);
      asm volatile("s_waitcnt vmcnt(4)" ::: "memory");
    } else {
      asm volatile("s_waitcnt vmcnt(0)" ::: "memory");
    }
    __builtin_amdgcn_sched_barrier(0);
    s16x8 af[4], bf[4];
    #pragma unroll
    for (int ta = 0; ta < 4; ta++)
      af[ta] = *(const s16x8*)&aoL[(t*4 + ta)*512 + lane*8];
    #pragma unroll
    for (int tb = 0; tb < 4; tb++)
      bf[tb] = *(const s16x8*)&bufR[(w*4 + tb)*512 + lane*8];
    __builtin_amdgcn_s_setprio(1);
    #pragma unroll
    for (int ta = 0; ta < 4; ta++)
      #pragma unroll
      for (int tb = 0; tb < 4; tb++)
        acc[ta][tb] = __builtin_amdgcn_mfma_f32_16x16x32_bf16(af[ta], bf[tb], acc[ta][tb], 0, 0, 0);
    __builtin_amdgcn_s_setprio(0);
  }

  // epilogue: f32 stores (4 rows x 64B segments per instr) + bias
  float pbv[4];
  #pragma unroll
  for (int tb = 0; tb < 4; tb++) pbv[tb] = pb[w*64 + tb*16 + l15];
  #pragma unroll
  for (int ta = 0; ta < 4; ta++)
    #pragma unroll
    for (int tb = 0; tb < 4; tb++)
      #pragma unroll
      for (int j = 0; j < 4; j++) {
        int row = ta*16 + g*4 + j;
        int col = w*64 + tb*16 + l15;
        out[((size_t)b*64 + row)*512 + col] = acc[ta][tb][j] + pbv[tb];
      }
}

extern "C" void kernel_launch(void* const* d_in, const int* in_sizes, int n_in,
                              void* d_out, int out_size, void* d_ws, size_t ws_size,
                              hipStream_t stream) {
  const float* x      = (const float*)d_in[0];
  const float* qkv_w  = (const float*)d_in[1];
  const float* table  = (const float*)d_in[2];
  const float* proj_w = (const float*)d_in[3];
  const float* proj_b = (const float*)d_in[4];
  const int*   rel_idx = (const int*)d_in[5];

  const size_t S1 = S1_ELEMS;
  const size_t need = (4*S1 + 786432 + 262144)*sizeof(ushort_t) + 65536*sizeof(float);
  if (ws_size < need) return;

  ushort_t* qh  = (ushort_t*)d_ws;
  ushort_t* kh  = qh + S1;
  ushort_t* vt  = kh + S1;
  ushort_t* xh  = vt + S1;
  ushort_t* wqh = xh + S1;
  ushort_t* wph = wqh + 786432;
  float*    bias = (float*)(wph + 262144);

  hipFuncSetAttribute((const void*)k_gemm_qkv,
                      hipFuncAttributeMaxDynamicSharedMemorySize, 131072);
  hipFuncSetAttribute((const void*)k_attn_proj,
                      hipFuncAttributeMaxDynamicSharedMemorySize, 131072);

  k_prep<<<3712, 256, 0, stream>>>(x, xh, qkv_w, wqh, proj_w, wph, table, rel_idx, bias);
  k_gemm_qkv<<<2352, 512, 131072, stream>>>(xh, wqh, qh, kh, vt);
  k_attn_proj<<<1568, 512, 131072, stream>>>(qh, kh, vt, bias, wph, proj_b, (float*)d_out);
}

// Round 15
// 505.214 us; speedup vs baseline: 1.1135x; 1.1111x over previous
//
#include <hip/hip_runtime.h>
#include <stdint.h>

typedef unsigned short ushort_t;
typedef unsigned long long u64_t;
typedef __attribute__((ext_vector_type(4))) float f32x4;
typedef __attribute__((ext_vector_type(8))) short s16x8;

#define S1_ELEMS ((size_t)1568*64*512)   // 51,380,224 elements per q/k/v/x buffer

// ---------- bf16 helpers (RNE)
__device__ __forceinline__ ushort_t f2bf(float f) {
  unsigned u = __builtin_bit_cast(unsigned, f);
  u = u + 0x7fffu + ((u >> 16) & 1u);
  return (ushort_t)(u >> 16);
}

// ---------- async global->LDS, 16B per lane (dest = uniform base + lane*16)
__device__ __forceinline__ void gl_lds16(const ushort_t* g, ushort_t* l) {
  typedef __attribute__((address_space(1))) void gvoid;
  typedef __attribute__((address_space(3))) void lvoid;
  __builtin_amdgcn_global_load_lds((gvoid*)(ushort_t*)g, (lvoid*)l, 16, 0, 0);
}

// ---------- kernel 1: merged prep — x/wq/wp f32->bf16 convert + bias gather.
__global__ void k_prep(const float* __restrict__ x, ushort_t* __restrict__ xh,
                       const float* __restrict__ wq, ushort_t* __restrict__ wqh,
                       const float* __restrict__ wp, ushort_t* __restrict__ wph,
                       const float* __restrict__ table, const int* __restrict__ rel_idx,
                       float* __restrict__ bias) {
  int blk = blockIdx.x, tid = threadIdx.x;
  if (blk < 3136) {
    long i0 = (long)blk*256 + tid;
    #pragma unroll
    for (int rep = 0; rep < 8; rep++) {
      long i = i0 + (long)rep*802816;
      float4 v0 = ((const float4*)x)[2*i];
      float4 v1 = ((const float4*)x)[2*i + 1];
      s16x8 pk;
      pk[0] = (short)f2bf(v0.x); pk[1] = (short)f2bf(v0.y);
      pk[2] = (short)f2bf(v0.z); pk[3] = (short)f2bf(v0.w);
      pk[4] = (short)f2bf(v1.x); pk[5] = (short)f2bf(v1.y);
      pk[6] = (short)f2bf(v1.z); pk[7] = (short)f2bf(v1.w);
      *(s16x8*)&xh[i*8] = pk;
    }
  } else if (blk < 3648) {
    const float* src; ushort_t* dst; long i;
    if (blk < 3520) { src = wq; dst = wqh; i = (long)(blk - 3136)*256 + tid; }
    else            { src = wp; dst = wph; i = (long)(blk - 3520)*256 + tid; }
    float4 v0 = ((const float4*)src)[2*i];
    float4 v1 = ((const float4*)src)[2*i + 1];
    s16x8 pk;
    pk[0] = (short)f2bf(v0.x); pk[1] = (short)f2bf(v0.y);
    pk[2] = (short)f2bf(v0.z); pk[3] = (short)f2bf(v0.w);
    pk[4] = (short)f2bf(v1.x); pk[5] = (short)f2bf(v1.y);
    pk[6] = (short)f2bf(v1.z); pk[7] = (short)f2bf(v1.w);
    *(s16x8*)&dst[i*8] = pk;
  } else {
    int i0 = ((blk - 3648)*256 + tid)*4;     // 65536 total
    #pragma unroll
    for (int j = 0; j < 4; j++) {
      int i = i0 + j;
      int h = i >> 12, rc = i & 4095;
      bias[i] = table[rel_idx[rc] * 16 + h];
    }
  }
}

// ================= QKV GEMM loop: 256x256 tile, 8 waves (2x4), BK=64, 8 K-tiles.
// 4 phases per K-tile, counted vmcnt(8) twice per K-tile (never 0 until tail),
// raw s_barrier, setprio around MFMA. LDS: 2 bufs x (A 256x64 | B 256x64) = 131072 B.
struct GemmCtx {
  ushort_t* lds;
  const ushort_t *pA0, *pA1, *pB0, *pB1;
  int w, lane, wm, wn;
};

template<int BUFP, int KH, int RH, int SSEL, int SBUFP, int SU, int VM>
__device__ __forceinline__ void phase(const GemmCtx& C, f32x4 (&acc)[8][4], s16x8 (&bf)[4], int stau) {
  s16x8 af[4];
  #pragma unroll
  for (int t = 0; t < 4; t++)
    af[t] = *(const s16x8*)&C.lds[BUFP*32768 + ((C.wm*8 + RH*4 + t)*2 + KH)*512 + C.lane*8];
  if constexpr (RH == 0) {
    #pragma unroll
    for (int t = 0; t < 4; t++)
      bf[t] = *(const s16x8*)&C.lds[BUFP*32768 + 16384 + ((C.wn*4 + t)*2 + KH)*512 + C.lane*8];
  }
  if constexpr (SSEL == 0) {
    gl_lds16(C.pA0 + stau*64 + SU*32, C.lds + SBUFP*32768 + (4*C.w + SU)*512);
    gl_lds16(C.pA1 + stau*64 + SU*32, C.lds + SBUFP*32768 + (4*C.w + 2 + SU)*512);
  } else if constexpr (SSEL == 1) {
    gl_lds16(C.pB0 + stau*64 + SU*32, C.lds + SBUFP*32768 + 16384 + (4*C.w + SU)*512);
    gl_lds16(C.pB1 + stau*64 + SU*32, C.lds + SBUFP*32768 + 16384 + (4*C.w + 2 + SU)*512);
  }
  if constexpr (VM == 8) asm volatile("s_waitcnt vmcnt(8)" ::: "memory");
  else if constexpr (VM == 4) asm volatile("s_waitcnt vmcnt(4)" ::: "memory");
  else if constexpr (VM == 0) asm volatile("s_waitcnt vmcnt(0)" ::: "memory");
  __builtin_amdgcn_s_barrier();
  __builtin_amdgcn_s_setprio(1);
  #pragma unroll
  for (int ta = 0; ta < 4; ta++)
    #pragma unroll
    for (int tb = 0; tb < 4; tb++)
      acc[RH*4 + ta][tb] = __builtin_amdgcn_mfma_f32_16x16x32_bf16(af[ta], bf[tb], acc[RH*4 + ta][tb], 0, 0, 0);
  __builtin_amdgcn_s_setprio(0);
  __builtin_amdgcn_s_barrier();
}

// per K-tile tau: q1 stages A-kh1(tau+1), q2 B-kh1(tau+1) [vmcnt],
//                 q3 stages A-kh0(tau+2), q4 B-kh0(tau+2) [vmcnt]
template<int BUFP, bool S12, bool S34, int VM2, int VM4>
__device__ __forceinline__ void ktile(const GemmCtx& C, f32x4 (&acc)[8][4], int tau) {
  s16x8 bf[4];
  phase<BUFP, 0, 0, S12 ? 0 : -1, BUFP^1, 1, -1 >(C, acc, bf, tau + 1);
  phase<BUFP, 0, 1, S12 ? 1 : -1, BUFP^1, 1, VM2>(C, acc, bf, tau + 1);
  phase<BUFP, 1, 0, S34 ? 0 : -1, BUFP,   0, -1 >(C, acc, bf, tau + 2);
  phase<BUFP, 1, 1, S34 ? 1 : -1, BUFP,   0, VM4>(C, acc, bf, tau + 2);
}

__global__ __launch_bounds__(512, 2) void k_gemm_qkv(
    const ushort_t* __restrict__ xh, const ushort_t* __restrict__ wh,
    ushort_t* __restrict__ qh, ushort_t* __restrict__ kh, ushort_t* __restrict__ vt) {
  extern __shared__ __align__(16) ushort_t lds[];
  const int tid = threadIdx.x, w = tid >> 6, lane = tid & 63;
  const int g = lane >> 4, l15 = lane & 15;
  const int wm = w >> 2, wn = w & 3;
  int flat = blockIdx.x;                 // 2352 = 8*294, bijective XCD swizzle
  int swz = (flat & 7) * 294 + (flat >> 3);
  int bx = swz % 6, by = swz / 6;        // bx fastest -> A-panel L2 reuse per XCD

  GemmCtx C;
  C.lds = lds;
  C.pA0 = xh + ((size_t)by*256 + (size_t)(2*w)*16 + l15)*512 + g*8;
  C.pA1 = C.pA0 + 16*512;
  C.pB0 = wh + ((size_t)bx*256 + (size_t)(2*w)*16 + l15)*512 + g*8;
  C.pB1 = C.pB0 + 16*512;
  C.w = w; C.lane = lane; C.wm = wm; C.wn = wn;

  f32x4 acc[8][4];
  #pragma unroll
  for (int r = 0; r < 8; r++)
    #pragma unroll
    for (int c = 0; c < 4; c++) acc[r][c] = (f32x4){0.f, 0.f, 0.f, 0.f};

  // prologue: tile0 (both halves) + tile1 kh0; keep last 4 issues in flight
  gl_lds16(C.pA0 +  0, lds + (4*w + 0)*512);
  gl_lds16(C.pA1 +  0, lds + (4*w + 2)*512);
  gl_lds16(C.pB0 +  0, lds + 16384 + (4*w + 0)*512);
  gl_lds16(C.pB1 +  0, lds + 16384 + (4*w + 2)*512);
  gl_lds16(C.pA0 + 32, lds + (4*w + 1)*512);
  gl_lds16(C.pA1 + 32, lds + (4*w + 3)*512);
  gl_lds16(C.pB0 + 32, lds + 16384 + (4*w + 1)*512);
  gl_lds16(C.pB1 + 32, lds + 16384 + (4*w + 3)*512);
  gl_lds16(C.pA0 + 64, lds + 32768 + (4*w + 0)*512);
  gl_lds16(C.pA1 + 64, lds + 32768 + (4*w + 2)*512);
  gl_lds16(C.pB0 + 64, lds + 32768 + 16384 + (4*w + 0)*512);
  gl_lds16(C.pB1 + 64, lds + 32768 + 16384 + (4*w + 2)*512);
  asm volatile("s_waitcnt vmcnt(4)" ::: "memory");
  __builtin_amdgcn_s_barrier();

  for (int kt = 0; kt < 6; kt += 2) {
    ktile<0, true, true, 8, 8>(C, acc, kt);
    ktile<1, true, true, 8, 8>(C, acc, kt + 1);
  }
  ktile<0, true,  false, 8, 4>(C, acc, 6);   // tail: vmcnt(4) guards tile7 kh0
  ktile<1, false, false, 0, -1>(C, acc, 7);  // tail: vmcnt(0) guards tile7 kh1

  // ---- epilogue: acc -> LDS (swizzled, conflict-free), coalesced stores.
  // 32 regions (b_i*8+h_i) x 2048 elems = 128 KiB. bx: 0,1->q  2,3->k  4,5->v(T)
  asm volatile("" ::: "memory");
  const int sel = bx >> 1;
  if (sel < 2) {
    #pragma unroll
    for (int ra = 0; ra < 8; ra++)
      #pragma unroll
      for (int tb = 0; tb < 4; tb++)
        #pragma unroll
        for (int j = 0; j < 4; j++) {
          int row = wm*128 + ra*16 + g*4 + j;
          int col = wn*64 + tb*16 + l15;
          int r = (row >> 6)*8 + (col >> 5);
          int n = row & 63, d = col & 31;
          int byte = r*4096 + ((n*64 + d*2) ^ ((n & 12) << 3));
          *(ushort_t*)((char*)lds + byte) = f2bf(acc[ra][tb][j]);
        }
  } else {
    #pragma unroll
    for (int ra = 0; ra < 8; ra++)
      #pragma unroll
      for (int tb = 0; tb < 4; tb++) {
        int row0 = wm*128 + ra*16 + g*4;
        int col = wn*64 + tb*16 + l15;
        int r = (row0 >> 6)*8 + (col >> 5);
        int n0 = row0 & 63, d = col & 31;
        u64_t pk = (u64_t)f2bf(acc[ra][tb][0])
                 | ((u64_t)f2bf(acc[ra][tb][1]) << 16)
                 | ((u64_t)f2bf(acc[ra][tb][2]) << 32)
                 | ((u64_t)f2bf(acc[ra][tb][3]) << 48);
        int byte = r*4096 + ((d*128 + n0*2) ^ ((d & 7) << 4) ^ (((((d >> 3) ^ (n0 >> 3))) & 1) << 6));
        *(u64_t*)((char*)lds + byte) = pk;
      }
  }
  asm volatile("s_waitcnt lgkmcnt(0)" ::: "memory");
  __builtin_amdgcn_s_barrier();
  ushort_t* dst = (sel == 0) ? qh : (sel == 1) ? kh : vt;
  const int hbase = (bx & 1) * 8;
  #pragma unroll
  for (int it = 0; it < 16; it++) {
    int cg = it*512 + tid;
    int r = cg >> 8, inner = cg & 255;
    int byte;
    if (sel < 2) byte = r*4096 + ((inner*16) ^ (((inner >> 2) & 12) << 3));
    else         byte = r*4096 + ((inner*16) ^ (((inner >> 3) & 7) << 4) ^ ((((inner >> 6) ^ inner) & 1) << 6));
    s16x8 v = *(const s16x8*)((const char*)lds + byte);
    int b = by*4 + (r >> 3), h = hbase + (r & 7);
    *(s16x8*)&dst[(size_t)(b*16 + h)*2048 + inner*8] = v;
  }
}

// ================= shared 256x256 BK=64 loop (proj; r6/r11 structure).
__device__ __forceinline__ void gemm256_loop(
    ushort_t* lds, const ushort_t* pA, const ushort_t* pB,
    int w, int lane, int wm, int wn, f32x4 (&acc)[8][4]) {
  #pragma unroll
  for (int q = 0; q < 2; q++) {
    gl_lds16(pA + q*8192 +  0, lds + ((2*w + q)*2 + 0)*512);
    gl_lds16(pA + q*8192 + 32, lds + ((2*w + q)*2 + 1)*512);
    gl_lds16(pB + q*8192 +  0, lds + 16384 + ((2*w + q)*2 + 0)*512);
    gl_lds16(pB + q*8192 + 32, lds + 16384 + ((2*w + q)*2 + 1)*512);
  }
  asm volatile("s_waitcnt vmcnt(0)" ::: "memory");
  __builtin_amdgcn_s_barrier();

  for (int tau = 0; tau < 8; ++tau) {
    ushort_t* bufR = lds + (tau & 1)*32768;
    ushort_t* bufW = lds + ((tau & 1) ^ 1)*32768;
    if (tau < 7) {
      int ko = (tau + 1)*64;
      #pragma unroll
      for (int q = 0; q < 2; q++) {
        gl_lds16(pA + q*8192 + ko,      bufW + ((2*w + q)*2 + 0)*512);
        gl_lds16(pA + q*8192 + ko + 32, bufW + ((2*w + q)*2 + 1)*512);
        gl_lds16(pB + q*8192 + ko,      bufW + 16384 + ((2*w + q)*2 + 0)*512);
        gl_lds16(pB + q*8192 + ko + 32, bufW + 16384 + ((2*w + q)*2 + 1)*512);
      }
    }
    s16x8 af[4][2], bf[4][2];
    #pragma unroll
    for (int t = 0; t < 4; t++)
      #pragma unroll
      for (int kh = 0; kh < 2; kh++) {
        af[t][kh] = *(const s16x8*)&bufR[((wm*8 + t)*2 + kh)*512 + lane*8];
        bf[t][kh] = *(const s16x8*)&bufR[16384 + ((wn*4 + t)*2 + kh)*512 + lane*8];
      }
    __builtin_amdgcn_s_barrier();
    asm volatile("s_waitcnt lgkmcnt(0)" ::: "memory");
    __builtin_amdgcn_sched_barrier(0);
    __builtin_amdgcn_s_setprio(1);
    #pragma unroll
    for (int t = 0; t < 4; t++)
      #pragma unroll
      for (int tb = 0; tb < 4; tb++) {
        acc[t][tb] = __builtin_amdgcn_mfma_f32_16x16x32_bf16(af[t][0], bf[tb][0], acc[t][tb], 0, 0, 0);
        acc[t][tb] = __builtin_amdgcn_mfma_f32_16x16x32_bf16(af[t][1], bf[tb][1], acc[t][tb], 0, 0, 0);
      }
    __builtin_amdgcn_s_setprio(0);
    s16x8 ag[4][2];
    #pragma unroll
    for (int t = 0; t < 4; t++)
      #pragma unroll
      for (int kh = 0; kh < 2; kh++)
        ag[t][kh] = *(const s16x8*)&bufR[((wm*8 + 4 + t)*2 + kh)*512 + lane*8];
    asm volatile("s_waitcnt lgkmcnt(0)" ::: "memory");
    __builtin_amdgcn_sched_barrier(0);
    __builtin_amdgcn_s_setprio(1);
    #pragma unroll
    for (int t = 0; t < 4; t++)
      #pragma unroll
      for (int tb = 0; tb < 4; tb++) {
        acc[4 + t][tb] = __builtin_amdgcn_mfma_f32_16x16x32_bf16(ag[t][0], bf[tb][0], acc[4 + t][tb], 0, 0, 0);
        acc[4 + t][tb] = __builtin_amdgcn_mfma_f32_16x16x32_bf16(ag[t][1], bf[tb][1], acc[4 + t][tb], 0, 0, 0);
      }
    __builtin_amdgcn_s_setprio(0);
    asm volatile("s_waitcnt vmcnt(0)" ::: "memory");
    __builtin_amdgcn_s_barrier();
  }
}

// ================= proj GEMM: 256x256, f32 2-pass swizzled epilogue (r11 config).
__global__ __launch_bounds__(512, 2) void k_gemm_proj(
    const ushort_t* __restrict__ ah, const ushort_t* __restrict__ wh,
    const float* __restrict__ pb, float* __restrict__ out) {
  extern __shared__ __align__(16) ushort_t lds[];
  const int tid = threadIdx.x, w = tid >> 6, lane = tid & 63;
  const int g = lane >> 4, l15 = lane & 15;
  const int wm = w >> 2, wn = w & 3;
  int flat = blockIdx.x;                 // 784 = 8*98, bijective XCD swizzle
  int swz = (flat & 7) * 98 + (flat >> 3);
  int bx = swz & 1, by = swz >> 1;

  const ushort_t* pA = ah + ((size_t)by*256 + (size_t)(2*w)*16 + l15)*512 + g*8;
  const ushort_t* pB = wh + ((size_t)bx*256 + (size_t)(2*w)*16 + l15)*512 + g*8;

  f32x4 acc[8][4];
  #pragma unroll
  for (int r = 0; r < 8; r++)
    #pragma unroll
    for (int c = 0; c < 4; c++) acc[r][c] = (f32x4){0.f, 0.f, 0.f, 0.f};

  gemm256_loop(lds, pA, pB, w, lane, wm, wn, acc);

  asm volatile("" ::: "memory");
  #pragma unroll
  for (int p = 0; p < 2; p++) {
    if (p) { asm volatile("" ::: "memory"); __builtin_amdgcn_s_barrier(); }
    if (wm == p) {
      #pragma unroll
      for (int ra = 0; ra < 8; ra++)
        #pragma unroll
        for (int tb = 0; tb < 4; tb++)
          #pragma unroll
          for (int j = 0; j < 4; j++) {
            int row = ra*16 + g*4 + j;          // local 0-127
            int col = wn*64 + tb*16 + l15;
            int byte = (row*1024 + col*4) ^ ((row & 12) << 2) ^ ((row & 8) << 3);
            *(float*)((char*)lds + byte) = acc[ra][tb][j];
          }
    }
    asm volatile("s_waitcnt lgkmcnt(0)" ::: "memory");
    __builtin_amdgcn_s_barrier();
    #pragma unroll
    for (int it = 0; it < 16; it++) {
      int cg = it*512 + tid;
      int row = cg >> 6, c16 = cg & 63;
      int byte = row*1024 + ((c16*16) ^ ((row & 12) << 2) ^ ((row & 8) << 3));
      f32x4 v = *(const f32x4*)((const char*)lds + byte);
      int ncol = bx*256 + c16*4;
      f32x4 pbv = *(const f32x4*)&pb[ncol];
      v = v + pbv;
      *(f32x4*)&out[(size_t)(by*256 + p*128 + row)*512 + ncol] = v;
    }
  }
}

// ---------- kernel 3: attention. Block = 4 windows x SAME head; q/k/v loads
// issued BEFORE bias staging. P scratch is fragment-linear per-wave (8 KiB/wave,
// conflict-free ds_read_b128 reads — r14-verified bit-identical layout);
// LDS total 50,176 B -> 3 blocks/CU (was 2).
__global__ __launch_bounds__(256) void k_attn(
    const ushort_t* __restrict__ qh, const ushort_t* __restrict__ kh,
    const ushort_t* __restrict__ vt, const float* __restrict__ bias,
    ushort_t* __restrict__ aoh) {
  __shared__ ushort_t plds[4][4096];       // fragment-linear P, per wave
  __shared__ float blds[64*68];            // pitch 68 -> only free 2-way conflicts
  const int tid = threadIdx.x, w = tid >> 6, lane = tid & 63;
  const int g = lane >> 4, l15 = lane & 15;
  const int h = blockIdx.x & 15;
  const int b = (blockIdx.x >> 4)*4 + w;   // 392 b-groups x 16 heads
  const size_t base = (size_t)(b*16 + h) * 2048;

  // issue-early: q/k/v fragment loads (global->reg), consumed after the barrier
  s16x8 qf[4], kf[4];
  #pragma unroll
  for (int t = 0; t < 4; t++) {
    size_t o = base + (size_t)(t*16 + l15)*32 + g*8;
    qf[t] = *(const s16x8*)&qh[o];
    kf[t] = *(const s16x8*)&kh[o];
  }
  s16x8 vf[2][2];
  #pragma unroll
  for (int kt = 0; kt < 2; kt++)
    #pragma unroll
    for (int nt = 0; nt < 2; nt++)
      vf[kt][nt] = *(const s16x8*)&vt[base + (size_t)(nt*16 + l15)*64 + kt*32 + g*8];

  // cooperative bias stage: 4096 f32, 16 per thread
  const float* bh_ = bias + ((size_t)h << 12);
  #pragma unroll
  for (int it = 0; it < 4; it++) {
    int idx = it*1024 + tid*4;
    int rr = idx >> 6, cc = idx & 63;
    *(f32x4*)&blds[rr*68 + cc] = *(const f32x4*)&bh_[idx];
  }
  __syncthreads();

  f32x4 s[4][4];
  #pragma unroll
  for (int r = 0; r < 4; r++)
    #pragma unroll
    for (int c = 0; c < 4; c++) s[r][c] = (f32x4){0.f,0.f,0.f,0.f};
  #pragma unroll
  for (int r = 0; r < 4; r++)
    #pragma unroll
    for (int c = 0; c < 4; c++)
      s[r][c] = __builtin_amdgcn_mfma_f32_16x16x32_bf16(qf[r], kf[c], s[r][c], 0, 0, 0);

  const float invs = 0.17677669529663687f;  // 1/sqrt(32)
  #pragma unroll
  for (int r = 0; r < 4; r++)
    #pragma unroll
    for (int c = 0; c < 4; c++)
      #pragma unroll
      for (int j = 0; j < 4; j++) {
        int rr = r*16 + g*4 + j, cc = c*16 + l15;
        s[r][c][j] = s[r][c][j]*invs + blds[rr*68 + cc];
      }

  #pragma unroll
  for (int r = 0; r < 4; r++)
    #pragma unroll
    for (int j = 0; j < 4; j++) {
      float mx = fmaxf(fmaxf(s[r][0][j], s[r][1][j]), fmaxf(s[r][2][j], s[r][3][j]));
      mx = fmaxf(mx, __shfl_xor(mx, 1));
      mx = fmaxf(mx, __shfl_xor(mx, 2));
      mx = fmaxf(mx, __shfl_xor(mx, 4));
      mx = fmaxf(mx, __shfl_xor(mx, 8));
      float p0 = __expf(s[r][0][j]-mx), p1 = __expf(s[r][1][j]-mx);
      float p2 = __expf(s[r][2][j]-mx), p3 = __expf(s[r][3][j]-mx);
      float sum = p0 + p1 + p2 + p3;
      sum += __shfl_xor(sum, 1);
      sum += __shfl_xor(sum, 2);
      sum += __shfl_xor(sum, 4);
      sum += __shfl_xor(sum, 8);
      float rv = 1.0f / sum;
      s[r][0][j] = p0*rv; s[r][1][j] = p1*rv; s[r][2][j] = p2*rv; s[r][3][j] = p3*rv;
    }

  // P store: fragment-linear per-wave scratch (r14-verified mapping)
  ushort_t* Pw = plds[w];
  asm volatile("s_waitcnt lgkmcnt(0)" ::: "memory");
  __builtin_amdgcn_sched_barrier(0);
  #pragma unroll
  for (int r = 0; r < 4; r++)
    #pragma unroll
    for (int c = 0; c < 4; c++)
      #pragma unroll
      for (int j = 0; j < 4; j++) {
        int idx = ((c >> 1)*4 + r)*512 + ((((c & 1)*2) + (l15 >> 3))*16 + g*4 + j)*8 + (l15 & 7);
        Pw[idx] = f2bf(s[r][c][j]);
      }
  asm volatile("s_waitcnt lgkmcnt(0)" ::: "memory");
  __builtin_amdgcn_sched_barrier(0);

  // P read (lane-linear, conflict-free) + PV
  s16x8 pf[4][2];
  #pragma unroll
  for (int ta = 0; ta < 4; ta++)
    #pragma unroll
    for (int kt = 0; kt < 2; kt++)
      pf[ta][kt] = *(const s16x8*)&Pw[(kt*4 + ta)*512 + lane*8];

  f32x4 o[4][2];
  #pragma unroll
  for (int ta = 0; ta < 4; ta++)
    #pragma unroll
    for (int nt = 0; nt < 2; nt++) o[ta][nt] = (f32x4){0.f,0.f,0.f,0.f};
  #pragma unroll
  for (int ta = 0; ta < 4; ta++)
    #pragma unroll
    for (int nt = 0; nt < 2; nt++)
      #pragma unroll
      for (int kt = 0; kt < 2; kt++)
        o[ta][nt] = __builtin_amdgcn_mfma_f32_16x16x32_bf16(pf[ta][kt], vf[kt][nt], o[ta][nt], 0, 0, 0);

  #pragma unroll
  for (int ta = 0; ta < 4; ta++)
    #pragma unroll
    for (int nt = 0; nt < 2; nt++)
      #pragma unroll
      for (int j = 0; j < 4; j++) {
        int rr = ta*16 + g*4 + j, dd = nt*16 + l15;
        aoh[((size_t)b*64 + rr)*512 + h*32 + dd] = f2bf(o[ta][nt][j]);
      }
}

extern "C" void kernel_launch(void* const* d_in, const int* in_sizes, int n_in,
                              void* d_out, int out_size, void* d_ws, size_t ws_size,
                              hipStream_t stream) {
  const float* x      = (const float*)d_in[0];
  const float* qkv_w  = (const float*)d_in[1];
  const float* table  = (const float*)d_in[2];
  const float* proj_w = (const float*)d_in[3];
  const float* proj_b = (const float*)d_in[4];
  const int*   rel_idx = (const int*)d_in[5];

  const size_t S1 = S1_ELEMS;
  const size_t need = (4*S1 + 786432 + 262144)*sizeof(ushort_t) + 65536*sizeof(float);
  if (ws_size < need) return;

  ushort_t* qh  = (ushort_t*)d_ws;
  ushort_t* kh  = qh + S1;
  ushort_t* vt  = kh + S1;
  ushort_t* xh  = vt + S1;        // reused as attention-out after QKV GEMM
  ushort_t* wqh = xh + S1;
  ushort_t* wph = wqh + 786432;
  float*    bias = (float*)(wph + 262144);
  ushort_t* aoh = xh;

  hipFuncSetAttribute((const void*)k_gemm_qkv,
                      hipFuncAttributeMaxDynamicSharedMemorySize, 131072);
  hipFuncSetAttribute((const void*)k_gemm_proj,
                      hipFuncAttributeMaxDynamicSharedMemorySize, 131072);

  k_prep<<<3712, 256, 0, stream>>>(x, xh, qkv_w, wqh, proj_w, wph, table, rel_idx, bias);
  k_gemm_qkv<<<2352, 512, 131072, stream>>>(xh, wqh, qh, kh, vt);
  k_attn<<<6272, 256, 0, stream>>>(qh, kh, vt, bias, aoh);
  k_gemm_proj<<<784, 512, 131072, stream>>>(aoh, wph, proj_b, (float*)d_out);
}